// Round 2
// 1168.022 us; speedup vs baseline: 1.0946x; 1.0946x over previous
//
#include <hip/hip_runtime.h>
#include <cstdint>
#include <cstddef>

#define IN_F 4096
#define OUT_F 4096
#define MTOT 16384   // 4 * 4096 rows
#define NBLKS 128    // IN_F / 32

typedef __bf16 bf16x8 __attribute__((ext_vector_type(8)));
typedef float f32x4 __attribute__((ext_vector_type(4)));
typedef const __attribute__((address_space(1))) void* gas_cvp;
typedef __attribute__((address_space(3))) void* las_vp;

__device__ __forceinline__ unsigned short f2bf(float f) {
  unsigned u = __builtin_bit_cast(unsigned, f);
  u += 0x7fffu + ((u >> 16) & 1u);   // round-to-nearest-even
  return (unsigned short)(u >> 16);
}

// ---------- Cayley: Q[n] = (I - S)^-1 (I + S),  S = 0.5 (R - R^T) ----------
__global__ void cayley_kernel(const float* __restrict__ R, float* __restrict__ Q) {
  __shared__ float M[32][66];
  const int n = blockIdx.x;
  const int t = threadIdx.x;
  const int i = t >> 5, j = t & 31;
  const float* Rb = R + n * 1024;
  const float s = 0.5f * (Rb[i * 32 + j] - Rb[j * 32 + i]);
  M[i][j]      = (i == j ? 1.0f : 0.0f) - s;  // A = I - S
  M[i][32 + j] = (i == j ? 1.0f : 0.0f) + s;  // B = I + S
  __syncthreads();
  for (int k = 0; k < 32; ++k) {
    const float pivinv = 1.0f / M[k][k];
    const float fik = M[i][k];
    const float mk1 = M[k][j] * pivinv;
    const float mk2 = M[k][32 + j] * pivinv;
    __syncthreads();
    if (i == k) {
      M[i][j] = mk1;
      M[i][32 + j] = mk2;
    } else {
      M[i][j]      -= fik * mk1;
      M[i][32 + j] -= fik * mk2;
    }
    __syncthreads();
  }
  Q[n * 1024 + i * 32 + j] = M[i][32 + j];
}

// ---------- Dequant W[o, g*8+j] = codebooks[0, codes[o,g,0], j] * scales[o] --
__global__ void dequant_kernel(const int* __restrict__ codes,
                               const float* __restrict__ cb,
                               const float* __restrict__ scales,
                               unsigned short* __restrict__ W) {
  const int idx = blockIdx.x * 256 + threadIdx.x;  // o*512 + g
  const int o = idx >> 9;
  const int code = codes[idx];
  const float s = scales[o];
  const float4* cp = (const float4*)(cb + (size_t)code * 8);
  const float4 a = cp[0], b = cp[1];
  uint4 p;
  p.x = (unsigned)f2bf(a.x * s) | ((unsigned)f2bf(a.y * s) << 16);
  p.y = (unsigned)f2bf(a.z * s) | ((unsigned)f2bf(a.w * s) << 16);
  p.z = (unsigned)f2bf(b.x * s) | ((unsigned)f2bf(b.y * s) << 16);
  p.w = (unsigned)f2bf(b.z * s) | ((unsigned)f2bf(b.w * s) << 16);
  ((uint4*)W)[idx] = p;
}

// ---------- Rotate: xr[m, n*32+c] = sum_j x[m, n*32+j] * Q[n][j][c] ---------
__global__ __launch_bounds__(256) void rotate_kernel(
    const float* __restrict__ x, const float* __restrict__ Q,
    unsigned short* __restrict__ xr) {
  __shared__ float Qs[1024];
  const int n = blockIdx.y;
  const int t = threadIdx.x;
#pragma unroll
  for (int i = 0; i < 4; ++i) Qs[t + i * 256] = Q[n * 1024 + t + i * 256];
  __syncthreads();
  const long m = (long)blockIdx.x * 256 + t;
  const float4* xp = (const float4*)(x + m * IN_F + n * 32);
  float4 xv[8];
#pragma unroll
  for (int j4 = 0; j4 < 8; ++j4) xv[j4] = xp[j4];
  float4 acc[8] = {};
  const float* xs = (const float*)xv;
#pragma unroll
  for (int j = 0; j < 32; ++j) {
    const float xj = xs[j];
#pragma unroll
    for (int c4 = 0; c4 < 8; ++c4) {
      const float4 q = ((const float4*)Qs)[j * 8 + c4];
      acc[c4].x += xj * q.x;
      acc[c4].y += xj * q.y;
      acc[c4].z += xj * q.z;
      acc[c4].w += xj * q.w;
    }
  }
  uint4* op = (uint4*)(xr + m * IN_F + n * 32);
#pragma unroll
  for (int g = 0; g < 4; ++g) {
    const float4 a = acc[2 * g], b = acc[2 * g + 1];
    uint4 p;
    p.x = (unsigned)f2bf(a.x) | ((unsigned)f2bf(a.y) << 16);
    p.y = (unsigned)f2bf(a.z) | ((unsigned)f2bf(a.w) << 16);
    p.z = (unsigned)f2bf(b.x) | ((unsigned)f2bf(b.y) << 16);
    p.w = (unsigned)f2bf(b.z) | ((unsigned)f2bf(b.w) << 16);
    op[g] = p;
  }
}

// ---------- GEMM v2: C[m,n] = sum_k A[m,k]*B[n,k] + bias[n] -----------------
// 256x256 tile, BK=32, 8 waves (2x4), ring-4 LDS pipeline (128 KiB).
// Iteration kt: issue global_load_lds for tile kt+3 (into slot last read at
// kt-1), ds_read 12 b128 frags + 32 MFMA on tile kt, then s_waitcnt vmcnt(8)
// (tile kt+1 landed; tiles kt+2/kt+3 = 8 loads stay in flight ACROSS the
// barrier) + one raw s_barrier. Counted vmcnt, never 0 in the main loop
// (T3+T4); setprio around the MFMA cluster (T5).
// LDS swizzle: row has 4x16B chunks; lds chunk j of row holds source chunk
// j ^ ((row>>1)&3); reader uses chunk = kg ^ ((lr>>1)&3). Source is
// pre-permuted (global_load_lds dest must stay linear, rule #21).
// R1 FIX: staging base soff = ri*512 elements (64 slots * 8 elem/slot), was
// ri*256 -> overlapping writes + upper half of every tile never staged -> NaN.
#define G_BM 256
#define G_BN 256
#define G_BK 32
#define G_KT 128   // 4096 / 32

__global__ __launch_bounds__(512, 2) void gemm_kernel(
    const __bf16* __restrict__ A, const __bf16* __restrict__ B,
    const float* __restrict__ bias, float* __restrict__ C) {
  __shared__ __attribute__((aligned(16))) __bf16 As[4][G_BM * G_BK];
  __shared__ __attribute__((aligned(16))) __bf16 Bs[4][G_BN * G_BK];

  const int t = threadIdx.x;
  const int l = t & 63;
  const int w = t >> 6;          // wave 0..7
  const int wm = w >> 2;         // 0..1  (M half)
  const int wn = w & 3;          // 0..3  (N quarter)
  const int lr = l & 15;
  const int kg = l >> 4;

  // XCD-aware bijective swizzle: nwg = 1024 = 8 * 128
  const int bid = blockIdx.x;
  const int wg = (bid & 7) * 128 + (bid >> 3);
  const int bx = wg & 15;        // N tile 0..15
  const int by = wg >> 4;        // M tile 0..63
  const long m0 = (long)by * G_BM;
  const long n0 = (long)bx * G_BN;

  const __bf16* Abase = A + m0 * IN_F;
  const __bf16* Bbase = B + n0 * IN_F;

  // Staging offsets (K-invariant). Instruction ri = w*2+q fills 16B slots
  // [ri*64, ri*64+64); slot s -> row = s>>2, lds chunk j = s&3,
  // source chunk = j ^ ((row>>1)&3). LDS element base = ri*64*8 = ri*512.
  int goff[2], soff[2];
#pragma unroll
  for (int q = 0; q < 2; ++q) {
    const int ri = w * 2 + q;          // 0..15
    const int s = ri * 64 + l;         // 16B slot 0..1023
    const int row = s >> 2;            // 0..255
    const int jj = s & 3;
    const int csrc = jj ^ ((row >> 1) & 3);
    goff[q] = row * IN_F + csrc * 8;   // element offset in global
    soff[q] = ri * 512;                // wave-uniform LDS element base (R1 fix)
  }

  // Fragment LDS offsets (row % 16 == lr -> (row>>1)&3 == (lr>>1)&3)
  const int chunk = kg ^ ((lr >> 1) & 3);
  int aoff[8], boff[4];
#pragma unroll
  for (int i = 0; i < 8; ++i) aoff[i] = (wm * 128 + i * 16 + lr) * G_BK + chunk * 8;
#pragma unroll
  for (int j = 0; j < 4; ++j) boff[j] = (wn * 64 + j * 16 + lr) * G_BK + chunk * 8;

  f32x4 acc[8][4] = {};

#define STAGE(buf, kt) do {                                                   \
    const __bf16* Ak_ = Abase + (kt) * G_BK;                                  \
    const __bf16* Bk_ = Bbase + (kt) * G_BK;                                  \
    _Pragma("unroll")                                                         \
    for (int q_ = 0; q_ < 2; ++q_) {                                          \
      __builtin_amdgcn_global_load_lds((gas_cvp)(Ak_ + goff[q_]),             \
                                       (las_vp)(&As[(buf)][0] + soff[q_]), 16, 0, 0); \
      __builtin_amdgcn_global_load_lds((gas_cvp)(Bk_ + goff[q_]),             \
                                       (las_vp)(&Bs[(buf)][0] + soff[q_]), 16, 0, 0); \
    }                                                                         \
  } while (0)

#define COMPUTE(buf) do {                                                     \
    bf16x8 af_[8], bf_[4];                                                    \
    _Pragma("unroll")                                                         \
    for (int i_ = 0; i_ < 8; ++i_)                                            \
      af_[i_] = *(const bf16x8*)(&As[(buf)][0] + aoff[i_]);                   \
    _Pragma("unroll")                                                         \
    for (int j_ = 0; j_ < 4; ++j_)                                            \
      bf_[j_] = *(const bf16x8*)(&Bs[(buf)][0] + boff[j_]);                   \
    __builtin_amdgcn_s_setprio(1);                                            \
    _Pragma("unroll")                                                         \
    for (int i_ = 0; i_ < 8; ++i_)                                            \
      _Pragma("unroll")                                                       \
      for (int j_ = 0; j_ < 4; ++j_)                                          \
        acc[i_][j_] = __builtin_amdgcn_mfma_f32_16x16x32_bf16(                \
            af_[i_], bf_[j_], acc[i_][j_], 0, 0, 0);                          \
    __builtin_amdgcn_s_setprio(0);                                            \
  } while (0)

#define TILE_SYNC(n) do {                                                     \
    asm volatile("s_waitcnt vmcnt(" #n ")" ::: "memory");                     \
    __builtin_amdgcn_s_barrier();                                             \
    asm volatile("" ::: "memory");                                            \
  } while (0)

  // Prologue: tiles 0..2 in flight; tile 0 landed before first compute.
  STAGE(0, 0);
  STAGE(1, 1);
  STAGE(2, 2);
  TILE_SYNC(8);

  // Main loop: kt = 0..123 (124 = 31*4 clean unroll-4 -> constant buf idx).
#pragma unroll 4
  for (int kt = 0; kt < G_KT - 4; ++kt) {
    STAGE((kt + 3) & 3, kt + 3);
    COMPUTE(kt & 3);
    TILE_SYNC(8);       // tile kt+1 landed; kt+2, kt+3 still in flight
  }
  // kt = 124
  STAGE(3, 127);
  COMPUTE(0);
  TILE_SYNC(8);         // 125 landed; 126,127 in flight
  // kt = 125
  COMPUTE(1);
  TILE_SYNC(4);         // 126 landed; 127 in flight
  // kt = 126
  COMPUTE(2);
  TILE_SYNC(0);         // 127 landed
  // kt = 127
  COMPUTE(3);

#undef STAGE
#undef COMPUTE
#undef TILE_SYNC

  // Epilogue: D layout col = lane&15, row = (lane>>4)*4 + reg.
#pragma unroll
  for (int j = 0; j < 4; ++j) {
    const long gn = n0 + wn * 64 + j * 16 + lr;
    const float bv = bias[gn];
#pragma unroll
    for (int i = 0; i < 8; ++i) {
      const long gm = m0 + wm * 128 + i * 16 + kg * 4;
#pragma unroll
      for (int r = 0; r < 4; ++r) {
        C[(gm + r) * (long)OUT_F + gn] = acc[i][j][r] + bv;
      }
    }
  }
}

extern "C" void kernel_launch(void* const* d_in, const int* in_sizes, int n_in,
                              void* d_out, int out_size, void* d_ws, size_t ws_size,
                              hipStream_t stream) {
  const float* x         = (const float*)d_in[0];  // (4,4096,4096) f32
  const float* oft_r     = (const float*)d_in[1];  // (128,32,32) f32
  const int*   codes     = (const int*)d_in[2];    // (4096,512,1) i32
  const float* codebooks = (const float*)d_in[3];  // (1,65536,8) f32
  const float* scales    = (const float*)d_in[4];  // (4096,1) f32
  const float* bias      = (const float*)d_in[5];  // (4096,) f32
  float* out = (float*)d_out;                      // (4,4096,4096) f32

  char* ws = (char*)d_ws;
  float* Q = (float*)ws;                                   // 512 KB
  unsigned short* XR = (unsigned short*)(ws + (1 << 19));  // 128 MB bf16
  unsigned short* W  = (unsigned short*)(ws + (1 << 19) + (size_t)MTOT * IN_F * 2);  // 32 MB

  cayley_kernel<<<NBLKS, 1024, 0, stream>>>(oft_r, Q);
  dequant_kernel<<<(OUT_F * (IN_F / 8)) / 256, 256, 0, stream>>>(codes, codebooks, scales, W);
  rotate_kernel<<<dim3(MTOT / 256, NBLKS), 256, 0, stream>>>(x, Q, XR);
  gemm_kernel<<<dim3((MTOT / G_BM) * (OUT_F / G_BN)), 512, 0, stream>>>(
      (const __bf16*)XR, (const __bf16*)W, bias, out);
}

// Round 3
// 1063.628 us; speedup vs baseline: 1.2021x; 1.0981x over previous
//
#include <hip/hip_runtime.h>
#include <cstdint>
#include <cstddef>

#define IN_F 4096
#define OUT_F 4096
#define MTOT 16384   // 4 * 4096 rows
#define NBLKS 128    // IN_F / 32

typedef __bf16 bf16x8 __attribute__((ext_vector_type(8)));
typedef float f32x4 __attribute__((ext_vector_type(4)));
typedef const __attribute__((address_space(1))) void* gas_cvp;
typedef __attribute__((address_space(3))) void* las_vp;

__device__ __forceinline__ unsigned short f2bf(float f) {
  unsigned u = __builtin_bit_cast(unsigned, f);
  u += 0x7fffu + ((u >> 16) & 1u);   // round-to-nearest-even
  return (unsigned short)(u >> 16);
}

// ---------- Cayley: Q[n] = (I - S)^-1 (I + S),  S = 0.5 (R - R^T) ----------
__global__ void cayley_kernel(const float* __restrict__ R, float* __restrict__ Q) {
  __shared__ float M[32][66];
  const int n = blockIdx.x;
  const int t = threadIdx.x;
  const int i = t >> 5, j = t & 31;
  const float* Rb = R + n * 1024;
  const float s = 0.5f * (Rb[i * 32 + j] - Rb[j * 32 + i]);
  M[i][j]      = (i == j ? 1.0f : 0.0f) - s;  // A = I - S
  M[i][32 + j] = (i == j ? 1.0f : 0.0f) + s;  // B = I + S
  __syncthreads();
  for (int k = 0; k < 32; ++k) {
    const float pivinv = 1.0f / M[k][k];
    const float fik = M[i][k];
    const float mk1 = M[k][j] * pivinv;
    const float mk2 = M[k][32 + j] * pivinv;
    __syncthreads();
    if (i == k) {
      M[i][j] = mk1;
      M[i][32 + j] = mk2;
    } else {
      M[i][j]      -= fik * mk1;
      M[i][32 + j] -= fik * mk2;
    }
    __syncthreads();
  }
  Q[n * 1024 + i * 32 + j] = M[i][32 + j];
}

// ---------- Dequant + rotate-fold into W ------------------------------------
// out = (x Q_bd) W^T = x (Q_bd W^T)^T, so
// W'[o, n*32+j] = sum_c Q[n][j][c] * W[o, n*32+c],  W = dequant(codes)*scale.
// Thread = one o-row for one n-block; Q[n] broadcast from LDS (uniform reads).
__global__ __launch_bounds__(256) void dequant_rotw_kernel(
    const int* __restrict__ codes, const float* __restrict__ cb,
    const float* __restrict__ scales, const float* __restrict__ Q,
    unsigned short* __restrict__ W2) {
  __shared__ float Qs[1024];
  const int n = blockIdx.y;
  const int t = threadIdx.x;
#pragma unroll
  for (int i = 0; i < 4; ++i) Qs[t + i * 256] = Q[n * 1024 + t + i * 256];
  __syncthreads();
  const int o = blockIdx.x * 256 + t;
  const float s = scales[o];
  float wv[32];
#pragma unroll
  for (int g = 0; g < 4; ++g) {
    const int code = codes[o * 512 + n * 4 + g];
    const float4* cp = (const float4*)(cb + (size_t)code * 8);
    const float4 a = cp[0], b = cp[1];
    wv[g * 8 + 0] = a.x * s; wv[g * 8 + 1] = a.y * s;
    wv[g * 8 + 2] = a.z * s; wv[g * 8 + 3] = a.w * s;
    wv[g * 8 + 4] = b.x * s; wv[g * 8 + 5] = b.y * s;
    wv[g * 8 + 6] = b.z * s; wv[g * 8 + 7] = b.w * s;
  }
  unsigned po[16];
#pragma unroll
  for (int jp = 0; jp < 16; ++jp) {
    float r[2];
#pragma unroll
    for (int h = 0; h < 2; ++h) {
      const int j = jp * 2 + h;
      float a = 0.0f;
#pragma unroll
      for (int c4 = 0; c4 < 8; ++c4) {
        const float4 q = ((const float4*)Qs)[j * 8 + c4];
        a += q.x * wv[c4 * 4 + 0] + q.y * wv[c4 * 4 + 1] +
             q.z * wv[c4 * 4 + 2] + q.w * wv[c4 * 4 + 3];
      }
      r[h] = a;
    }
    po[jp] = (unsigned)f2bf(r[0]) | ((unsigned)f2bf(r[1]) << 16);
  }
  uint4* op = (uint4*)(W2 + (size_t)o * IN_F + n * 32);
#pragma unroll
  for (int g = 0; g < 4; ++g) {
    uint4 p;
    p.x = po[g * 4 + 0]; p.y = po[g * 4 + 1];
    p.z = po[g * 4 + 2]; p.w = po[g * 4 + 3];
    op[g] = p;
  }
}

// ---------- Convert x (f32) -> bf16, fully coalesced ------------------------
__global__ __launch_bounds__(256) void cvt_kernel(
    const float* __restrict__ x, unsigned short* __restrict__ xc) {
  const size_t i = (size_t)blockIdx.x * 256 + threadIdx.x;  // 8 elems/thread
  const float4* xp = (const float4*)x + i * 2;
  const float4 a = xp[0], b = xp[1];
  uint4 p;
  p.x = (unsigned)f2bf(a.x) | ((unsigned)f2bf(a.y) << 16);
  p.y = (unsigned)f2bf(a.z) | ((unsigned)f2bf(a.w) << 16);
  p.z = (unsigned)f2bf(b.x) | ((unsigned)f2bf(b.y) << 16);
  p.w = (unsigned)f2bf(b.z) | ((unsigned)f2bf(b.w) << 16);
  ((uint4*)xc)[i] = p;
}

// ---------- GEMM v3: phase-split ring-4 pipeline ----------------------------
// 256x256 tile, BK=32, 8 waves (2x4), ring-4 LDS (128 KiB), counted vmcnt.
// Each K-tile = 2 barrier-pair phases (m201-granularity: 16 MFMA, 4-8 ds_read,
// 2 gload_lds, 2 barriers per phase):
//   phase A: ds_read A[0-3],B[0-3]; stage A(kt+3); bar; [sched_bar] 16 MFMA; bar
//   phase B: ds_read A[4-7];       stage B(kt+3); vmcnt(8); bar; 16 MFMA; bar
// vmcnt(8): after staging kt+3, up to 12 loads in flight (tiles kt+1..kt+3);
// waiting to 8 retires tile kt+1 (in-order, m135) before the next tile reads.
// Stage-into-buf[(kt+3)&3]=buf[(kt-1)&3] is safe: last reads of that buffer
// (tile kt-1 phase B) complete before its MFMA (data dep), and the phase-B end
// barrier precedes the stage issue.
// LDS swizzle unchanged (16B-chunk XOR, matched involution on source + read).
#define G_BM 256
#define G_BN 256
#define G_BK 32
#define G_KT 128   // 4096 / 32

__global__ __launch_bounds__(512, 2) void gemm_kernel(
    const __bf16* __restrict__ A, const __bf16* __restrict__ B,
    const float* __restrict__ bias, float* __restrict__ C) {
  __shared__ __attribute__((aligned(16))) __bf16 As[4][G_BM * G_BK];
  __shared__ __attribute__((aligned(16))) __bf16 Bs[4][G_BM * G_BK];

  const int t = threadIdx.x;
  const int l = t & 63;
  const int w = t >> 6;          // wave 0..7
  const int wm = w >> 2;         // 0..1  (M half)
  const int wn = w & 3;          // 0..3  (N quarter)
  const int lr = l & 15;
  const int kg = l >> 4;

  // XCD-aware bijective swizzle: nwg = 1024 = 8 * 128
  const int bid = blockIdx.x;
  const int wg = (bid & 7) * 128 + (bid >> 3);
  const int bx = wg & 15;        // N tile 0..15
  const int by = wg >> 4;        // M tile 0..63
  const long m0 = (long)by * G_BM;
  const long n0 = (long)bx * G_BN;

  const __bf16* Abase = A + m0 * IN_F;
  const __bf16* Bbase = B + n0 * IN_F;

  // Staging offsets. Instruction ri = w*2+q fills 16B slots [ri*64, +64);
  // slot s -> row = s>>2, lds chunk j = s&3, source chunk = j ^ ((row>>1)&3).
  int goff[2], soff[2];
#pragma unroll
  for (int q = 0; q < 2; ++q) {
    const int ri = w * 2 + q;          // 0..15
    const int s = ri * 64 + l;         // 16B slot 0..1023
    const int row = s >> 2;            // 0..255
    const int jj = s & 3;
    const int csrc = jj ^ ((row >> 1) & 3);
    goff[q] = row * IN_F + csrc * 8;   // element offset in global
    soff[q] = ri * 512;                // wave-uniform LDS element base
  }

  // Fragment LDS offsets (row % 16 == lr -> (row>>1)&3 == (lr>>1)&3)
  const int chunk = kg ^ ((lr >> 1) & 3);
  int aoff[8], boff[4];
#pragma unroll
  for (int i = 0; i < 8; ++i) aoff[i] = (wm * 128 + i * 16 + lr) * G_BK + chunk * 8;
#pragma unroll
  for (int j = 0; j < 4; ++j) boff[j] = (wn * 64 + j * 16 + lr) * G_BK + chunk * 8;

  f32x4 acc[8][4] = {};

#define STAGE_A(buf, kt) do {                                                 \
    const __bf16* Ak_ = Abase + (kt) * G_BK;                                  \
    _Pragma("unroll")                                                         \
    for (int q_ = 0; q_ < 2; ++q_)                                            \
      __builtin_amdgcn_global_load_lds((gas_cvp)(Ak_ + goff[q_]),             \
                                       (las_vp)(&As[(buf)][0] + soff[q_]), 16, 0, 0); \
  } while (0)

#define STAGE_B(buf, kt) do {                                                 \
    const __bf16* Bk_ = Bbase + (kt) * G_BK;                                  \
    _Pragma("unroll")                                                         \
    for (int q_ = 0; q_ < 2; ++q_)                                            \
      __builtin_amdgcn_global_load_lds((gas_cvp)(Bk_ + goff[q_]),             \
                                       (las_vp)(&Bs[(buf)][0] + soff[q_]), 16, 0, 0); \
  } while (0)

#define VM_WAIT(n) asm volatile("s_waitcnt vmcnt(" #n ")" ::: "memory")

#define TILE(buf, skt, dostage, vmstmt) do {                                  \
    bf16x8 a0_[4], a1_[4], b_[4];                                             \
    /* ---- phase A ---- */                                                   \
    _Pragma("unroll")                                                         \
    for (int j_ = 0; j_ < 4; ++j_)                                            \
      b_[j_] = *(const bf16x8*)(&Bs[(buf)][0] + boff[j_]);                    \
    _Pragma("unroll")                                                         \
    for (int i_ = 0; i_ < 4; ++i_)                                            \
      a0_[i_] = *(const bf16x8*)(&As[(buf)][0] + aoff[i_]);                   \
    if (dostage) STAGE_A((skt) & 3, skt);                                     \
    __builtin_amdgcn_s_barrier();                                             \
    __builtin_amdgcn_sched_barrier(0);                                        \
    __builtin_amdgcn_s_setprio(1);                                            \
    _Pragma("unroll")                                                         \
    for (int i_ = 0; i_ < 4; ++i_)                                            \
      _Pragma("unroll")                                                       \
      for (int j_ = 0; j_ < 4; ++j_)                                          \
        acc[i_][j_] = __builtin_amdgcn_mfma_f32_16x16x32_bf16(                \
            a0_[i_], b_[j_], acc[i_][j_], 0, 0, 0);                           \
    __builtin_amdgcn_s_setprio(0);                                            \
    __builtin_amdgcn_s_barrier();                                             \
    /* ---- phase B ---- */                                                   \
    _Pragma("unroll")                                                         \
    for (int i_ = 0; i_ < 4; ++i_)                                            \
      a1_[i_] = *(const bf16x8*)(&As[(buf)][0] + aoff[4 + i_]);               \
    if (dostage) STAGE_B((skt) & 3, skt);                                     \
    vmstmt;                                                                   \
    __builtin_amdgcn_s_barrier();                                             \
    __builtin_amdgcn_sched_barrier(0);                                        \
    __builtin_amdgcn_s_setprio(1);                                            \
    _Pragma("unroll")                                                         \
    for (int i_ = 0; i_ < 4; ++i_)                                            \
      _Pragma("unroll")                                                       \
      for (int j_ = 0; j_ < 4; ++j_)                                          \
        acc[4 + i_][j_] = __builtin_amdgcn_mfma_f32_16x16x32_bf16(            \
            a1_[i_], b_[j_], acc[4 + i_][j_], 0, 0, 0);                       \
    __builtin_amdgcn_s_setprio(0);                                            \
    __builtin_amdgcn_s_barrier();                                             \
  } while (0)

  // Prologue: tiles 0..2 in flight (A then B per tile, in-order); tile 0
  // landed (vmcnt 8 = tiles 1,2 outstanding) before first read.
  STAGE_A(0, 0); STAGE_B(0, 0);
  STAGE_A(1, 1); STAGE_B(1, 1);
  STAGE_A(2, 2); STAGE_B(2, 2);
  VM_WAIT(8);
  __builtin_amdgcn_s_barrier();

#pragma unroll 4
  for (int kt = 0; kt < G_KT - 4; ++kt)
    TILE(kt & 3, kt + 3, 1, VM_WAIT(8));
  TILE(0, 127, 1, VM_WAIT(8));   // kt=124: stages tile 127; 125 landed
  TILE(1, 0, 0, VM_WAIT(4));     // kt=125: 126 landed
  TILE(2, 0, 0, VM_WAIT(0));     // kt=126: 127 landed
  TILE(3, 0, 0, (void)0);        // kt=127

#undef STAGE_A
#undef STAGE_B
#undef VM_WAIT
#undef TILE

  // Epilogue: D layout col = lane&15, row = (lane>>4)*4 + reg.
#pragma unroll
  for (int j = 0; j < 4; ++j) {
    const long gn = n0 + wn * 64 + j * 16 + lr;
    const float bv = bias[gn];
#pragma unroll
    for (int i = 0; i < 8; ++i) {
      const long gm = m0 + wm * 128 + i * 16 + kg * 4;
#pragma unroll
      for (int r = 0; r < 4; ++r) {
        C[(gm + r) * (long)OUT_F + gn] = acc[i][j][r] + bv;
      }
    }
  }
}

extern "C" void kernel_launch(void* const* d_in, const int* in_sizes, int n_in,
                              void* d_out, int out_size, void* d_ws, size_t ws_size,
                              hipStream_t stream) {
  const float* x         = (const float*)d_in[0];  // (4,4096,4096) f32
  const float* oft_r     = (const float*)d_in[1];  // (128,32,32) f32
  const int*   codes     = (const int*)d_in[2];    // (4096,512,1) i32
  const float* codebooks = (const float*)d_in[3];  // (1,65536,8) f32
  const float* scales    = (const float*)d_in[4];  // (4096,1) f32
  const float* bias      = (const float*)d_in[5];  // (4096,) f32
  float* out = (float*)d_out;                      // (4,4096,4096) f32

  char* ws = (char*)d_ws;
  float* Q = (float*)ws;                                   // 512 KB
  unsigned short* XC = (unsigned short*)(ws + (1 << 19));  // 128 MB bf16 x
  unsigned short* W2 = (unsigned short*)(ws + (1 << 19) + (size_t)MTOT * IN_F * 2);  // 32 MB

  cayley_kernel<<<NBLKS, 1024, 0, stream>>>(oft_r, Q);
  dequant_rotw_kernel<<<dim3(OUT_F / 256, NBLKS), 256, 0, stream>>>(
      codes, codebooks, scales, Q, W2);
  cvt_kernel<<<(MTOT * (size_t)IN_F) / (256 * 8), 256, 0, stream>>>(x, XC);
  gemm_kernel<<<dim3((MTOT / G_BM) * (OUT_F / G_BN)), 512, 0, stream>>>(
      (const __bf16*)XC, (const __bf16*)W2, bias, out);
}